// Round 1
// baseline (708.176 us; speedup 1.0000x reference)
//
#include <hip/hip_runtime.h>

typedef __attribute__((ext_vector_type(8))) short short8;
typedef __attribute__((ext_vector_type(4))) float f32x4;

#define NEG_SLOPE 0.02f

static __device__ __forceinline__ unsigned short f2bf(float f) {
    unsigned int u = __float_as_uint(f);
    u += 0x7fffu + ((u >> 16) & 1u);
    return (unsigned short)(u >> 16);
}

// ---------------- prep: weight transforms ----------------
// wT[ci][dy][dx][co] = conv_w[co][ci][dy][dx]   (36864 f32)
// pwb[o][k] = bf16(pred_w[o][k]) for o<24, 0 for 24<=o<32   (32*768 bf16)
__global__ __launch_bounds__(256) void prep_kernel(const float* __restrict__ conv_w,
                                                   const float* __restrict__ pred_w,
                                                   float* __restrict__ wT,
                                                   unsigned short* __restrict__ pwb) {
    int i = blockIdx.x * 256 + threadIdx.x;
    if (i < 36864) {
        int co = i & 63;
        int rest = i >> 6;                 // ci*9 + dy*3 + dx
        int dx = rest % 3, dy = (rest / 3) % 3, ci = rest / 9;
        wT[i] = conv_w[((co * 64 + ci) * 3 + dy) * 3 + dx];
    }
    if (i < 24576) {
        int o = i / 768, k = i - o * 768;
        float v = (o < 24) ? pred_w[o * 768 + k] : 0.0f;
        pwb[i] = f2bf(v);
    }
}

// ---------------- conv 3x3 + bias + leaky relu (f32 compute, bf16 NHWC out) ----------------
// grid: (128 rows y, 32 batches). block 256.
// thread: tx = tid&31 -> x0 = tx*4 ; cg = tid>>5 -> co0 = cg*8. acc[4][8].
__global__ __launch_bounds__(256) void conv_lrelu(const float* __restrict__ x,
                                                  const float* __restrict__ wT,
                                                  const float* __restrict__ cb,
                                                  unsigned short* __restrict__ h) {
    __shared__ float tile[32][3][132];   // [ci_chunk][dy row][x=-1..130]
    const int y = blockIdx.x;
    const int b = blockIdx.y;
    const int tid = threadIdx.x;
    const int tx = tid & 31, cg = tid >> 5;
    const int x0 = tx * 4, co0 = cg * 8;

    float acc[4][8];
#pragma unroll
    for (int xi = 0; xi < 4; ++xi)
#pragma unroll
        for (int j = 0; j < 8; ++j) acc[xi][j] = 0.0f;

    for (int cc = 0; cc < 2; ++cc) {
        __syncthreads();
        // stage 32 channels x 3 rows x 132 (x=-1..130), zero padded
        for (int i = tid; i < 32 * 3 * 132; i += 256) {
            int cl = i / 396;
            int rem = i - cl * 396;
            int r = rem / 132;
            int xx = rem - r * 132;
            int gy = y + r - 1, gx = xx - 1;
            float v = 0.0f;
            if (gy >= 0 && gy < 128 && gx >= 0 && gx < 128)
                v = x[(((size_t)b * 64 + cc * 32 + cl) * 128 + gy) * 128 + gx];
            tile[cl][r][xx] = v;
        }
        __syncthreads();

#pragma unroll 2
        for (int cl = 0; cl < 32; ++cl) {
            const int ci = cc * 32 + cl;
            const float* wbase = wT + ci * 576 + co0;   // + (dy*3+dx)*64
#pragma unroll
            for (int dy = 0; dy < 3; ++dy) {
                float in6[6];
                const float* tr = &tile[cl][dy][x0];
#pragma unroll
                for (int q = 0; q < 6; ++q) in6[q] = tr[q];
#pragma unroll
                for (int dx = 0; dx < 3; ++dx) {
                    const float4 wa = *(const float4*)(wbase + (dy * 3 + dx) * 64);
                    const float4 wb = *(const float4*)(wbase + (dy * 3 + dx) * 64 + 4);
#pragma unroll
                    for (int xi = 0; xi < 4; ++xi) {
                        const float v = in6[xi + dx];
                        acc[xi][0] = fmaf(v, wa.x, acc[xi][0]);
                        acc[xi][1] = fmaf(v, wa.y, acc[xi][1]);
                        acc[xi][2] = fmaf(v, wa.z, acc[xi][2]);
                        acc[xi][3] = fmaf(v, wa.w, acc[xi][3]);
                        acc[xi][4] = fmaf(v, wb.x, acc[xi][4]);
                        acc[xi][5] = fmaf(v, wb.y, acc[xi][5]);
                        acc[xi][6] = fmaf(v, wb.z, acc[xi][6]);
                        acc[xi][7] = fmaf(v, wb.w, acc[xi][7]);
                    }
                }
            }
        }
    }

    // epilogue: bias + leaky relu, pack 8 bf16 = 16B store, NHWC layout
    const float4 cba = *(const float4*)(cb + co0);
    const float4 cbb = *(const float4*)(cb + co0 + 4);
    float bias[8] = {cba.x, cba.y, cba.z, cba.w, cbb.x, cbb.y, cbb.z, cbb.w};
#pragma unroll
    for (int xi = 0; xi < 4; ++xi) {
        union { unsigned short u[8]; uint4 v; } o;
#pragma unroll
        for (int j = 0; j < 8; ++j) {
            float r = acc[xi][j] + bias[j];
            r = r > 0.0f ? r : NEG_SLOPE * r;
            o.u[j] = f2bf(r);
        }
        *(uint4*)&h[(((size_t)b * 128 + y) * 128 + (x0 + xi)) * 64 + co0] = o.v;
    }
}

// ---------------- gather + (pairs x 768)·(768 x 24) GEMM via MFMA ----------------
// pair = k*32 + b  (32000 pairs). wave handles 16 pairs, block = 4 waves = 64 pairs.
// A frag: lane holds h[pair(lane&15)] channels k=(lane>>4)*8..+7  (16B global load, NHWC bf16)
// B frag: pw_lds[o = lane&15 (+16)][k], XOR-swizzled rows to avoid 16-way bank conflict.
__global__ __launch_bounds__(256) void gather_gemm(const unsigned short* __restrict__ h,
                                                   const int* __restrict__ pos,
                                                   const unsigned short* __restrict__ pw,
                                                   const float* __restrict__ pred_b,
                                                   float* __restrict__ out) {
    __shared__ unsigned char pw_lds[32 * 1536];   // 32 rows x 768 bf16, swizzled
    const int tid = threadIdx.x;

    // stage pred_w bf16 into LDS with T2 swizzle: byte ^= (row&7)<<4
    for (int i = tid; i < 3072; i += 256) {       // 3072 chunks of 16B
        int row = i / 96, c = i - row * 96;
        int dst = row * 1536 + ((c * 16) ^ ((row & 7) << 4));
        *(uint4*)(pw_lds + dst) = ((const uint4*)pw)[i];
    }
    __syncthreads();

    const int wave = tid >> 6, lane = tid & 63;
    const int pair_base = blockIdx.x * 64 + wave * 16;
    const int prow = lane & 15;         // A row / B col within fragment
    const int kgrp = lane >> 4;         // k chunk: k = kgrp*8 + j
    const int pair = pair_base + prow;
    const int b = pair & 31;
    const unsigned short* hb = h + (size_t)b * 16384 * 64;

    const int swz0 = (prow & 7) << 4;
    const unsigned char* bro0 = pw_lds + prow * 1536;
    const unsigned char* bro1 = pw_lds + (prow + 16) * 1536;

    f32x4 acc0 = {0.f, 0.f, 0.f, 0.f};
    f32x4 acc1 = {0.f, 0.f, 0.f, 0.f};

#pragma unroll
    for (int l = 0; l < 12; ++l) {
        int2 pq = ((const int2*)pos)[pair * 12 + l];
        int px = pq.x < 0 ? 0 : (pq.x > 127 ? 127 : pq.x);
        int py = pq.y < 0 ? 0 : (pq.y > 127 ? 127 : pq.y);
        const unsigned short* pix = hb + (((size_t)py << 7) + px) * 64;
#pragma unroll
        for (int half = 0; half < 2; ++half) {
            const int c0 = half * 32 + kgrp * 8;
            short8 a = *(const short8*)(pix + c0);
            const int kb = (l * 64 + half * 32 + kgrp * 8) * 2;   // byte offset in row
            short8 b0 = *(const short8*)(bro0 + (kb ^ swz0));
            short8 b1 = *(const short8*)(bro1 + (kb ^ swz0));
            acc0 = __builtin_amdgcn_mfma_f32_16x16x32_bf16(a, b0, acc0, 0, 0, 0);
            acc1 = __builtin_amdgcn_mfma_f32_16x16x32_bf16(a, b1, acc1, 0, 0, 0);
        }
    }

    // epilogue: D row = pair offset (lane>>4)*4+r, col = o = lane&15
    const int o0 = lane & 15;
    const float bias0 = pred_b[o0];
    const float bias1 = (o0 + 16 < 24) ? pred_b[o0 + 16] : 0.0f;
#pragma unroll
    for (int r = 0; r < 4; ++r) {
        const int pout = pair_base + (lane >> 4) * 4 + r;
        out[(size_t)pout * 24 + o0] = acc0[r] + bias0;
        if (o0 + 16 < 24)
            out[(size_t)pout * 24 + o0 + 16] = acc1[r] + bias1;
    }
}

extern "C" void kernel_launch(void* const* d_in, const int* in_sizes, int n_in,
                              void* d_out, int out_size, void* d_ws, size_t ws_size,
                              hipStream_t stream) {
    const float* x      = (const float*)d_in[0];
    const int*   pos    = (const int*)d_in[1];
    const float* conv_w = (const float*)d_in[2];
    const float* conv_b = (const float*)d_in[3];
    const float* pred_w = (const float*)d_in[4];
    const float* pred_b = (const float*)d_in[5];
    float* out = (float*)d_out;

    char* ws = (char*)d_ws;
    unsigned short* h   = (unsigned short*)ws;                    // 32*128*128*64 bf16 = 67,108,864 B
    float*          wT  = (float*)(ws + 67108864);                // 36864 f32 = 147,456 B
    unsigned short* pwb = (unsigned short*)(ws + 67108864 + 147456); // 32*768 bf16 = 49,152 B

    prep_kernel<<<144, 256, 0, stream>>>(conv_w, pred_w, wT, pwb);
    conv_lrelu<<<dim3(128, 32), 256, 0, stream>>>(x, wT, conv_b, h);
    gather_gemm<<<500, 256, 0, stream>>>(h, pos, pwb, pred_b, out);
}

// Round 3
// 130.171 us; speedup vs baseline: 5.4404x; 5.4404x over previous
//
#include <hip/hip_runtime.h>

typedef __attribute__((ext_vector_type(8))) short short8;
typedef __attribute__((ext_vector_type(4))) float f32x4;

#define NEG_SLOPE 0.02f

static __device__ __forceinline__ unsigned short f2bf(float f) {
    unsigned int u = __float_as_uint(f);
    u += 0x7fffu + ((u >> 16) & 1u);
    return (unsigned short)(u >> 16);
}

// ---------------- prep: weight transforms ----------------
// wb[co][tap][ci]  bf16  (64*9*64)   from conv_w[co][ci][dy][dx]
// pwb[o][k] = bf16(pred_w[o][k]) for o<24, 0 pad to 32 rows  (32*768 bf16)
__global__ __launch_bounds__(256) void prep_kernel(const float* __restrict__ conv_w,
                                                   const float* __restrict__ pred_w,
                                                   unsigned short* __restrict__ wb,
                                                   unsigned short* __restrict__ pwb) {
    int i = blockIdx.x * 256 + threadIdx.x;
    if (i < 36864) {
        int ci = i & 63, tap = (i >> 6) % 9, co = i / 576;
        wb[i] = f2bf(conv_w[(co * 64 + ci) * 9 + tap]);
    }
    if (i < 24576) {
        int o = i / 768, k = i - o * 768;
        pwb[i] = f2bf(o < 24 ? pred_w[o * 768 + k] : 0.0f);
    }
}

// ---------------- conv 3x3 + bias + leaky relu via MFMA implicit GEMM ----------------
// block: one (b, y) output row: 128 px x 64 co. 256 thr = 4 waves, wave = 32 px x 64 co.
// 9 taps x 2 ci-chunks of 32; each (tap, chunk) is one 16x16x32 MFMA K-step.
//
// in_sm layout (bytes): row r stride 8320; pixel pair (xx>>1) stride 128 B;
// 8 slots of 16 B per pair; slot = ((xx&1)<<2 | chunk) ^ ((xx>>1)&7).
// Closed 3-bit XOR -> bijective within the pair, no overflow. A-frag ds_read_b128
// across 16 consecutive pixels covers all 8 slots twice -> 2-way (free).
#define IN_ROW 130           // pixel slots: xx = gx+1, gx in [-1,128]
#define ROW_BYTES (65 * 128) // 8320
__global__ __launch_bounds__(256) void conv_mfma(const float* __restrict__ x,
                                                 const unsigned short* __restrict__ wb,
                                                 const float* __restrict__ cb,
                                                 unsigned short* __restrict__ h) {
    __shared__ unsigned short w_sm[64 * 296];            // [co][288 + 8 pad]  37,888 B
    __shared__ unsigned char in_sm[3 * ROW_BYTES];       // 24,960 B

    // XCD-chunked swizzle: each XCD gets 16 contiguous y rows x all b
    const int id = blockIdx.x;
    const int xcd = id & 7, local = id >> 3;
    const int b = local & 31;
    const int y = (xcd << 4) + (local >> 5);

    const int tid = threadIdx.x;
    const int wave = tid >> 6, lane = tid & 63;
    const int lr = lane & 15, kg = lane >> 4;
    const int x0w = wave * 32;

    f32x4 acc[2][4];
#pragma unroll
    for (int m = 0; m < 2; ++m)
#pragma unroll
        for (int n = 0; n < 4; ++n) acc[m][n] = (f32x4){0.f, 0.f, 0.f, 0.f};

    // A-frag base pointers: 2 m-tiles x 3 dx (dy adds r*ROW_BYTES at use)
    const unsigned char* ab[2][3];
#pragma unroll
    for (int m = 0; m < 2; ++m)
#pragma unroll
        for (int dx = 0; dx < 3; ++dx) {
            int pix = x0w + m * 16 + lr + dx;
            int pair = pix >> 1, odd = pix & 1;
            int slot = ((odd << 2) | kg) ^ (pair & 7);
            ab[m][dx] = in_sm + pair * 128 + slot * 16;
        }
    const unsigned short* bb[4];
#pragma unroll
    for (int n = 0; n < 4; ++n) bb[n] = w_sm + (n * 16 + lr) * 296 + kg * 8;

    for (int cc = 0; cc < 2; ++cc) {
        __syncthreads();
        // ---- stage weights: [co][tap*32 + ci'] (+8 pad), 2304 x 16B ----
        for (int j = tid; j < 2304; j += 256) {
            int q = j & 3, tap = (j >> 2) % 9, co = j / 36;
            uint4 v = *(const uint4*)(wb + (co * 9 + tap) * 64 + cc * 32 + q * 8);
            *(uint4*)(w_sm + co * 296 + tap * 32 + q * 8) = v;
        }
        // ---- stage input: NCHW f32 -> bf16 pair-swizzled ----
        for (int j = tid; j < 1536; j += 256) {
            int g4 = j & 31, cp = (j >> 5) & 15, r = j >> 9;
            int gy = y + r - 1;
            int ci = cp * 2;                      // even channel within chunk
            float4 v0 = {0.f, 0.f, 0.f, 0.f}, v1 = v0;
            if (gy >= 0 && gy < 128) {
                const float* base = x + (((size_t)b * 64 + cc * 32 + ci) * 128 + gy) * 128 + g4 * 4;
                v0 = *(const float4*)base;
                v1 = *(const float4*)(base + 16384);   // channel ci+1
            }
            float a0[4] = {v0.x, v0.y, v0.z, v0.w};
            float a1[4] = {v1.x, v1.y, v1.z, v1.w};
            const int chunk = ci >> 3, within = (ci & 7) * 2;
#pragma unroll
            for (int t = 0; t < 4; ++t) {
                int xx = g4 * 4 + 1 + t;
                unsigned int p = (unsigned int)f2bf(a0[t]) | ((unsigned int)f2bf(a1[t]) << 16);
                int pair = xx >> 1, odd = xx & 1;
                int slot = ((odd << 2) | chunk) ^ (pair & 7);
                *(unsigned int*)(in_sm + r * ROW_BYTES + pair * 128 + slot * 16 + within) = p;
            }
        }
        // ---- zero-pad columns xx=0 and xx=129 ----
        for (int j = tid; j < 96; j += 256) {
            int r = j % 3, cp = (j / 3) % 16, xx = (j >= 48) ? 129 : 0;
            int ci = cp * 2;
            int pair = xx >> 1, odd = xx & 1;
            int slot = ((odd << 2) | (ci >> 3)) ^ (pair & 7);
            *(unsigned int*)(in_sm + r * ROW_BYTES + pair * 128 + slot * 16 + (ci & 7) * 2) = 0u;
        }
        __syncthreads();

        // ---- compute: 9 taps, each one K=32 MFMA step ----
#pragma unroll
        for (int t = 0; t < 9; ++t) {
            const int dy = t / 3, dx = t % 3;
            const int aoff = dy * ROW_BYTES;     // byte offset
            short8 a0 = *(const short8*)(ab[0][dx] + aoff);
            short8 a1 = *(const short8*)(ab[1][dx] + aoff);
#pragma unroll
            for (int n = 0; n < 4; ++n) {
                short8 bf = *(const short8*)(bb[n] + t * 32);
                acc[0][n] = __builtin_amdgcn_mfma_f32_16x16x32_bf16(a0, bf, acc[0][n], 0, 0, 0);
                acc[1][n] = __builtin_amdgcn_mfma_f32_16x16x32_bf16(a1, bf, acc[1][n], 0, 0, 0);
            }
        }
    }

    // ---- epilogue: bias + leaky relu, bf16 NHWC store ----
    float bias[4];
#pragma unroll
    for (int n = 0; n < 4; ++n) bias[n] = cb[n * 16 + lr];
    const size_t hrow = (size_t)(b * 128 + y) * 128;
#pragma unroll
    for (int m = 0; m < 2; ++m)
#pragma unroll
        for (int r = 0; r < 4; ++r) {
            const int p = x0w + m * 16 + kg * 4 + r;
            unsigned short* hp = h + (hrow + p) * 64 + lr;
#pragma unroll
            for (int n = 0; n < 4; ++n) {
                float v = acc[m][n][r] + bias[n];
                v = v > 0.0f ? v : NEG_SLOPE * v;
                hp[n * 16] = f2bf(v);
            }
        }
}

// ---------------- gather + (pairs x 768)·(768 x 24) GEMM via MFMA ----------------
__global__ __launch_bounds__(256) void gather_gemm(const unsigned short* __restrict__ h,
                                                   const int* __restrict__ pos,
                                                   const unsigned short* __restrict__ pw,
                                                   const float* __restrict__ pred_b,
                                                   float* __restrict__ out) {
    __shared__ unsigned char pw_lds[32 * 1536];   // 32 rows x 768 bf16, swizzled
    const int tid = threadIdx.x;

    for (int i = tid; i < 3072; i += 256) {       // 3072 chunks of 16B
        int row = i / 96, c = i - row * 96;
        int dst = row * 1536 + ((c * 16) ^ ((row & 7) << 4));
        *(uint4*)(pw_lds + dst) = ((const uint4*)pw)[i];
    }
    __syncthreads();

    const int wave = tid >> 6, lane = tid & 63;
    const int pair_base = blockIdx.x * 64 + wave * 16;
    const int prow = lane & 15;
    const int kgrp = lane >> 4;
    const int pair = pair_base + prow;
    const int b = pair & 31;
    const unsigned short* hb = h + (size_t)b * 16384 * 64;

    const int swz0 = (prow & 7) << 4;
    const unsigned char* bro0 = pw_lds + prow * 1536;
    const unsigned char* bro1 = pw_lds + (prow + 16) * 1536;

    f32x4 acc0 = {0.f, 0.f, 0.f, 0.f};
    f32x4 acc1 = {0.f, 0.f, 0.f, 0.f};

#pragma unroll
    for (int l = 0; l < 12; ++l) {
        int2 pq = ((const int2*)pos)[pair * 12 + l];
        int px = pq.x < 0 ? 0 : (pq.x > 127 ? 127 : pq.x);
        int py = pq.y < 0 ? 0 : (pq.y > 127 ? 127 : pq.y);
        const unsigned short* pix = hb + (((size_t)py << 7) + px) * 64;
#pragma unroll
        for (int half = 0; half < 2; ++half) {
            const int c0 = half * 32 + kgrp * 8;
            short8 a = *(const short8*)(pix + c0);
            const int kb = (l * 64 + half * 32 + kgrp * 8) * 2;
            short8 b0 = *(const short8*)(bro0 + (kb ^ swz0));
            short8 b1 = *(const short8*)(bro1 + (kb ^ swz0));
            acc0 = __builtin_amdgcn_mfma_f32_16x16x32_bf16(a, b0, acc0, 0, 0, 0);
            acc1 = __builtin_amdgcn_mfma_f32_16x16x32_bf16(a, b1, acc1, 0, 0, 0);
        }
    }

    const int o0 = lane & 15;
    const float bias0 = pred_b[o0];
    const float bias1 = (o0 + 16 < 24) ? pred_b[o0 + 16] : 0.0f;
#pragma unroll
    for (int r = 0; r < 4; ++r) {
        const int pout = pair_base + (lane >> 4) * 4 + r;
        out[(size_t)pout * 24 + o0] = acc0[r] + bias0;
        if (o0 + 16 < 24)
            out[(size_t)pout * 24 + o0 + 16] = acc1[r] + bias1;
    }
}

extern "C" void kernel_launch(void* const* d_in, const int* in_sizes, int n_in,
                              void* d_out, int out_size, void* d_ws, size_t ws_size,
                              hipStream_t stream) {
    const float* x      = (const float*)d_in[0];
    const int*   pos    = (const int*)d_in[1];
    const float* conv_w = (const float*)d_in[2];
    const float* conv_b = (const float*)d_in[3];
    const float* pred_w = (const float*)d_in[4];
    const float* pred_b = (const float*)d_in[5];
    float* out = (float*)d_out;

    char* ws = (char*)d_ws;
    unsigned short* h   = (unsigned short*)ws;                        // 67,108,864 B
    unsigned short* wb  = (unsigned short*)(ws + 67108864);           // 73,728 B
    unsigned short* pwb = (unsigned short*)(ws + 67108864 + 73728);   // 49,152 B

    prep_kernel<<<144, 256, 0, stream>>>(conv_w, pred_w, wb, pwb);
    conv_mfma<<<4096, 256, 0, stream>>>(x, wb, conv_b, h);
    gather_gemm<<<500, 256, 0, stream>>>(h, pos, pwb, pred_b, out);
}